// Round 6
// baseline (343.503 us; speedup 1.0000x reference)
//
#include <hip/hip_runtime.h>

#define NN 50000   // nodes
#define NE 600000  // edges
#define DF 128     // features
#define NB 16384   // pair batch

typedef short bf16x8 __attribute__((ext_vector_type(8)));
typedef float f32x4 __attribute__((ext_vector_type(4)));

__device__ __forceinline__ float bf2f(unsigned short u){
  return __uint_as_float(((unsigned int)u) << 16);
}
__device__ __forceinline__ unsigned short f2bf(float x){
  unsigned int b = __float_as_uint(x);
  return (unsigned short)((b + 0x7FFFu + ((b >> 16) & 1u)) >> 16);
}

// Original template symbol (defined, never launched).
__global__ void GraphSAGE_8504035246140_kernel(){ }

// ---- fused prelude: h cast | zero cnt/fill | zero stats | weight swizzle ----
__global__ __launch_bounds__(256) void k_prelude(
    const float* h_in, unsigned short* h_c,
    const float* Ws, const float* Wn, const float* W1,
    unsigned short* WsB, unsigned short* WnB, unsigned short* W1B,
    int* cnt, float* stats){
  int b = blockIdx.x, t = threadIdx.x;
  if (b < 3125){                       // 3125*256 == NN*DF/8 exactly
    int i = b * 256 + t;
    const float4* s = (const float4*)h_in;
    float4 v0 = s[i * 2], v1 = s[i * 2 + 1];
    unsigned short d[8] = {f2bf(v0.x), f2bf(v0.y), f2bf(v0.z), f2bf(v0.w),
                           f2bf(v1.x), f2bf(v1.y), f2bf(v1.z), f2bf(v1.w)};
    *(bf16x8*)(h_c + i * 8) = *(bf16x8*)d;
  } else if (b < 3516){
    int i = (b - 3125) * 256 + t;
    if (i < 2 * NN) cnt[i] = 0;        // cnt + fill (adjacent)
  } else if (b < 3518){
    int i = (b - 3516) * 256 + t;
    if (i < 512) stats[i] = 0.f;
  } else {
    int idx = (b - 3518) * 256 + t;    // 192 blocks -> 49152 threads
    if (idx < 2 * DF * DF){
      int layer = idx >> 14;
      int e = idx & (DF * DF - 1);
      int k = e >> 7, n = e & 127;
      int dst = layer * DF * DF + (((k >> 3) * 128 + n) << 3) + (k & 7);
      WsB[dst] = f2bf(Ws[idx]);
      WnB[dst] = f2bf(Wn[idx]);
    }
    if (idx < 3 * DF * DF){
      int k = idx >> 7, n = idx & 127; // W1: 384x128
      W1B[(((k >> 3) * 128 + n) << 3) + (k & 7)] = f2bf(W1[idx]);
    }
  }
}

// ---- CSR build ----
__global__ void k_hist(const int* dst, int* cnt){
  int e = blockIdx.x * 256 + threadIdx.x;
  if (e < NE) atomicAdd(&cnt[dst[e]], 1);
}
__global__ void k_scan1(const int* cnt, int* bsum){   // grid 196: block sums
  __shared__ int l[256];
  int t = threadIdx.x, i = blockIdx.x * 256 + t;
  l[t] = (i < NN) ? cnt[i] : 0;
  __syncthreads();
  for (int o = 128; o > 0; o >>= 1){
    if (t < o) l[t] += l[t + o];
    __syncthreads();
  }
  if (t == 0) bsum[blockIdx.x] = l[0];
}
// scan3: folds the global scan of bsum (196 values) into every block.
__global__ void k_scan3(const int* cnt, const int* bsum, int* rp, float* dinv){
  __shared__ int bs[256];
  __shared__ int l[256];
  int t = threadIdx.x, i = blockIdx.x * 256 + t;
  bs[t] = (t < 196) ? bsum[t] : 0;
  int v = (i < NN) ? cnt[i] : 0;
  l[t] = v;
  __syncthreads();
  for (int o = 1; o < 256; o <<= 1){
    int xb = (t >= o) ? bs[t - o] : 0;
    int xl = (t >= o) ? l[t - o] : 0;
    __syncthreads();
    bs[t] += xb; l[t] += xl;
    __syncthreads();
  }
  int base = (blockIdx.x == 0) ? 0 : bs[blockIdx.x - 1];
  if (i < NN){
    rp[i] = base + l[t] - v;
    dinv[i] = 1.0f / fmaxf((float)v, 1.0f);
    if (i == NN - 1) rp[NN] = base + l[t];
  }
}
__global__ void k_scatter(const int* src, const int* dst,
                          const int* rp, int* fill, int* perm){
  int e = blockIdx.x * 256 + threadIdx.x;
  if (e < NE){
    int d = dst[e];
    int pos = atomicAdd(&fill[d], 1);
    perm[rp[d] + pos] = src[e];
  }
}

// ---- FUSED layer: mean-aggregate (gather) into LDS, then MFMA GEMM ----
// Phase A: wave w aggregates nodes w*16..w*16+15 (one node at a time) with
// the uint4 gather: 16 lanes x 16B cover one 256B row; 4 row-slots -> 16
// edges per predicated batch (mean deg 12 => ~90% single batch). Reduction
// via shfl_xor(16,32); lanes rs==0 pack bf16 and write the mean row into
// LDS AG (row stride 136 shorts = 272B: keeps 16B alignment, ~2-way banks).
// Phase B: the original MFMA body, agg fragment read from LDS.
// Fusion removes the aggb global round-trip and hides GEMM under gather BW:
// 782 blocks x 4 waves = 12 waves/CU, each 4x1KB loads in flight -> demand
// far above the ~5.7 TB/s fabric ceiling observed for this gather.
__global__ __launch_bounds__(256) void k_layer_mfma(
    const unsigned short* hb, const int* rp, const int* perm,
    const float* dinv,
    const unsigned short* WsB, const unsigned short* WnB,
    const float* bias, unsigned short* hout){
  __shared__ __align__(16) unsigned short AG[64 * 136];
  int t = threadIdx.x;
  int w = t >> 6, l = t & 63;
  int rs = l >> 4, li = l & 15;        // row slot 0..3, 16B chunk 0..15
  const unsigned int* hq = (const unsigned int*)hb + li * 4;
  for (int jj = 0; jj < 16; ++jj){
    int lr = w * 16 + jj;
    int n = blockIdx.x * 64 + lr;
    float a0 = 0.f, a1 = 0.f, a2 = 0.f, a3 = 0.f;
    float a4 = 0.f, a5 = 0.f, a6 = 0.f, a7 = 0.f;
    float di = 0.f;
    if (n < NN){
      int s = rp[n], e = rp[n + 1];
      di = dinv[n];
      int i = s;
      for (; i + 16 <= e; i += 16){
        int p0 = perm[i + rs];
        int p1 = perm[i + 4 + rs];
        int p2 = perm[i + 8 + rs];
        int p3 = perm[i + 12 + rs];
        uint4 x0 = *(const uint4*)(hq + (size_t)p0 * 64);
        uint4 x1 = *(const uint4*)(hq + (size_t)p1 * 64);
        uint4 x2 = *(const uint4*)(hq + (size_t)p2 * 64);
        uint4 x3 = *(const uint4*)(hq + (size_t)p3 * 64);
        a0 += __uint_as_float(x0.x << 16); a1 += __uint_as_float(x0.x & 0xffff0000u);
        a2 += __uint_as_float(x0.y << 16); a3 += __uint_as_float(x0.y & 0xffff0000u);
        a4 += __uint_as_float(x0.z << 16); a5 += __uint_as_float(x0.z & 0xffff0000u);
        a6 += __uint_as_float(x0.w << 16); a7 += __uint_as_float(x0.w & 0xffff0000u);
        a0 += __uint_as_float(x1.x << 16); a1 += __uint_as_float(x1.x & 0xffff0000u);
        a2 += __uint_as_float(x1.y << 16); a3 += __uint_as_float(x1.y & 0xffff0000u);
        a4 += __uint_as_float(x1.z << 16); a5 += __uint_as_float(x1.z & 0xffff0000u);
        a6 += __uint_as_float(x1.w << 16); a7 += __uint_as_float(x1.w & 0xffff0000u);
        a0 += __uint_as_float(x2.x << 16); a1 += __uint_as_float(x2.x & 0xffff0000u);
        a2 += __uint_as_float(x2.y << 16); a3 += __uint_as_float(x2.y & 0xffff0000u);
        a4 += __uint_as_float(x2.z << 16); a5 += __uint_as_float(x2.z & 0xffff0000u);
        a6 += __uint_as_float(x2.w << 16); a7 += __uint_as_float(x2.w & 0xffff0000u);
        a0 += __uint_as_float(x3.x << 16); a1 += __uint_as_float(x3.x & 0xffff0000u);
        a2 += __uint_as_float(x3.y << 16); a3 += __uint_as_float(x3.y & 0xffff0000u);
        a4 += __uint_as_float(x3.z << 16); a5 += __uint_as_float(x3.z & 0xffff0000u);
        a6 += __uint_as_float(x3.w << 16); a7 += __uint_as_float(x3.w & 0xffff0000u);
      }
      if (i < e){
        int i0 = i + rs, i1 = i + 4 + rs, i2 = i + 8 + rs, i3 = i + 12 + rs;
        int p0 = perm[i0 < e ? i0 : s];
        int p1 = perm[i1 < e ? i1 : s];
        int p2 = perm[i2 < e ? i2 : s];
        int p3 = perm[i3 < e ? i3 : s];
        uint4 x0 = *(const uint4*)(hq + (size_t)p0 * 64);
        uint4 x1 = *(const uint4*)(hq + (size_t)p1 * 64);
        uint4 x2 = *(const uint4*)(hq + (size_t)p2 * 64);
        uint4 x3 = *(const uint4*)(hq + (size_t)p3 * 64);
        if (i0 < e){
          a0 += __uint_as_float(x0.x << 16); a1 += __uint_as_float(x0.x & 0xffff0000u);
          a2 += __uint_as_float(x0.y << 16); a3 += __uint_as_float(x0.y & 0xffff0000u);
          a4 += __uint_as_float(x0.z << 16); a5 += __uint_as_float(x0.z & 0xffff0000u);
          a6 += __uint_as_float(x0.w << 16); a7 += __uint_as_float(x0.w & 0xffff0000u);
        }
        if (i1 < e){
          a0 += __uint_as_float(x1.x << 16); a1 += __uint_as_float(x1.x & 0xffff0000u);
          a2 += __uint_as_float(x1.y << 16); a3 += __uint_as_float(x1.y & 0xffff0000u);
          a4 += __uint_as_float(x1.z << 16); a5 += __uint_as_float(x1.z & 0xffff0000u);
          a6 += __uint_as_float(x1.w << 16); a7 += __uint_as_float(x1.w & 0xffff0000u);
        }
        if (i2 < e){
          a0 += __uint_as_float(x2.x << 16); a1 += __uint_as_float(x2.x & 0xffff0000u);
          a2 += __uint_as_float(x2.y << 16); a3 += __uint_as_float(x2.y & 0xffff0000u);
          a4 += __uint_as_float(x2.z << 16); a5 += __uint_as_float(x2.z & 0xffff0000u);
          a6 += __uint_as_float(x2.w << 16); a7 += __uint_as_float(x2.w & 0xffff0000u);
        }
        if (i3 < e){
          a0 += __uint_as_float(x3.x << 16); a1 += __uint_as_float(x3.x & 0xffff0000u);
          a2 += __uint_as_float(x3.y << 16); a3 += __uint_as_float(x3.y & 0xffff0000u);
          a4 += __uint_as_float(x3.z << 16); a5 += __uint_as_float(x3.z & 0xffff0000u);
          a6 += __uint_as_float(x3.w << 16); a7 += __uint_as_float(x3.w & 0xffff0000u);
        }
      }
    }
    a0 += __shfl_xor(a0, 16); a1 += __shfl_xor(a1, 16);
    a2 += __shfl_xor(a2, 16); a3 += __shfl_xor(a3, 16);
    a4 += __shfl_xor(a4, 16); a5 += __shfl_xor(a5, 16);
    a6 += __shfl_xor(a6, 16); a7 += __shfl_xor(a7, 16);
    a0 += __shfl_xor(a0, 32); a1 += __shfl_xor(a1, 32);
    a2 += __shfl_xor(a2, 32); a3 += __shfl_xor(a3, 32);
    a4 += __shfl_xor(a4, 32); a5 += __shfl_xor(a5, 32);
    a6 += __shfl_xor(a6, 32); a7 += __shfl_xor(a7, 32);
    if (rs == 0){
      uint4 r;
      r.x = (unsigned int)f2bf(a0 * di) | ((unsigned int)f2bf(a1 * di) << 16);
      r.y = (unsigned int)f2bf(a2 * di) | ((unsigned int)f2bf(a3 * di) << 16);
      r.z = (unsigned int)f2bf(a4 * di) | ((unsigned int)f2bf(a5 * di) << 16);
      r.w = (unsigned int)f2bf(a6 * di) | ((unsigned int)f2bf(a7 * di) << 16);
      *(uint4*)(AG + lr * 136 + li * 8) = r;
    }
  }
  __syncthreads();
  // ---- Phase B: MFMA GEMM (agg fragment from LDS) ----
  int m = l & 15, q = l >> 4;
  int r0 = blockIdx.x * 64 + w * 16;
  int arow = r0 + m; if (arow > NN - 1) arow = NN - 1;
  const unsigned short* hp = hb + (size_t)arow * DF + q * 8;
  const unsigned short* ap = AG + (w * 16 + m) * 136 + q * 8;
  f32x4 acc[8];
  for (int ct = 0; ct < 8; ++ct){
    float bbc = bias[ct * 16 + m];
    acc[ct] = (f32x4){bbc, bbc, bbc, bbc};
  }
  for (int kt = 0; kt < 4; ++kt){
    bf16x8 a_h = *(const bf16x8*)(hp + kt * 32);
    bf16x8 a_g = *(const bf16x8*)(ap + kt * 32);
    int kg = kt * 4 + q;
    for (int ct = 0; ct < 8; ++ct){
      bf16x8 b_s = *(const bf16x8*)(WsB + (((kg << 7) + ct * 16 + m) << 3));
      bf16x8 b_n = *(const bf16x8*)(WnB + (((kg << 7) + ct * 16 + m) << 3));
      acc[ct] = __builtin_amdgcn_mfma_f32_16x16x32_bf16(a_h, b_s, acc[ct], 0, 0, 0);
      acc[ct] = __builtin_amdgcn_mfma_f32_16x16x32_bf16(a_g, b_n, acc[ct], 0, 0, 0);
    }
  }
  for (int ct = 0; ct < 8; ++ct){
    int col = ct * 16 + m;
    for (int reg = 0; reg < 4; ++reg){
      int row = r0 + q * 4 + reg;
      if (row < NN) hout[(size_t)row * DF + col] = f2bf(fmaxf(acc[ct][reg], 0.f));
    }
  }
}

// ---- pair GEMM via MFMA + fused BN column stats; src/tar via blockIdx.y ----
__global__ __launch_bounds__(256) void k_pair_mfma(
    const unsigned short* h2,
    const int* x1, const int* x2, const int* x1t, const int* x2t,
    const unsigned short* W1B, const float* b1, float* zbase, float* stats){
  __shared__ __align__(16) unsigned short F[64 * 392];
  __shared__ float csum[128], csq[128];
  int g = blockIdx.y;
  const int* ia = g ? x1t : x1;
  const int* ib = g ? x2t : x2;
  float* z = zbase + (size_t)g * NB * DF;
  int t = threadIdx.x;
  if (t < 128){ csum[t] = 0.f; csq[t] = 0.f; }
  int r0 = blockIdx.x * 64;
  int i = t >> 2, qq = t & 3;
  int r = r0 + i;
  int a = ia[r], b = ib[r];
  const unsigned short* pa = h2 + (size_t)a * DF + qq * 32;
  const unsigned short* pb = h2 + (size_t)b * DF + qq * 32;
  unsigned short* fr = F + i * 392;
  for (int jj = 0; jj < 4; ++jj){
    bf16x8 va = *(const bf16x8*)(pa + jj * 8);
    bf16x8 vb = *(const bf16x8*)(pb + jj * 8);
    *(bf16x8*)(fr + qq * 32 + jj * 8) = va;
    *(bf16x8*)(fr + 128 + qq * 32 + jj * 8) = vb;
    unsigned short d[8];
    for (int e = 0; e < 8; ++e){
      float fa = bf2f((unsigned short)va[e]);
      float fb = bf2f((unsigned short)vb[e]);
      d[e] = f2bf(fabsf(fa - fb));
    }
    *(bf16x8*)(fr + 256 + qq * 32 + jj * 8) = *(bf16x8*)d;
  }
  __syncthreads();
  int w = t >> 6, l = t & 63;
  int m = l & 15, q = l >> 4;
  int rl = w * 16 + m;
  f32x4 acc[8];
  for (int ct = 0; ct < 8; ++ct){
    float bbc = b1[ct * 16 + m];
    acc[ct] = (f32x4){bbc, bbc, bbc, bbc};
  }
  for (int kt = 0; kt < 12; ++kt){
    bf16x8 af = *(const bf16x8*)(F + rl * 392 + kt * 32 + q * 8);
    int kg = kt * 4 + q;
    for (int ct = 0; ct < 8; ++ct){
      bf16x8 bfr = *(const bf16x8*)(W1B + (((kg << 7) + ct * 16 + m) << 3));
      acc[ct] = __builtin_amdgcn_mfma_f32_16x16x32_bf16(af, bfr, acc[ct], 0, 0, 0);
    }
  }
  for (int ct = 0; ct < 8; ++ct){
    int col = ct * 16 + m;
    int row = r0 + w * 16 + q * 4;
    float s = 0.f, s2 = 0.f;
    for (int reg = 0; reg < 4; ++reg){
      float v = acc[ct][reg];
      z[(size_t)(row + reg) * DF + col] = v;
      s += v; s2 += v * v;
    }
    atomicAdd(&csum[col], s);
    atomicAdd(&csq[col], s2);
  }
  __syncthreads();
  if (t < 128){
    atomicAdd(&stats[g * 256 + t], csum[t]);
    atomicAdd(&stats[g * 256 + 128 + t], csq[t]);
  }
}

// ---- fused BN-normalize + relu + (src only) h_p GEMM, barrier-free ----
// One wave per 4 rows; 2 columns per lane; h_p dot via shfl_xor reduction.
__global__ __launch_bounds__(256) void k_norm_hp(
    const float* zbase, const float* stats,
    const float* gamma, const float* beta,
    const float* W2, const float* b2, float* mmd_base, float* hp){
  int g = blockIdx.y;
  int t = threadIdx.x;
  int w = t >> 6, l = t & 63;
  int c0 = l * 2, c1 = c0 + 1;
  float m0 = stats[g * 256 + c0] * (1.0f / NB);
  float m1 = stats[g * 256 + c1] * (1.0f / NB);
  float v0 = stats[g * 256 + 128 + c0] * (1.0f / NB) - m0 * m0;
  float v1 = stats[g * 256 + 128 + c1] * (1.0f / NB) - m1 * m1;
  float is0 = 1.0f / sqrtf(v0 + 1e-5f);
  float is1 = 1.0f / sqrtf(v1 + 1e-5f);
  float ga0 = gamma[c0], ga1 = gamma[c1];
  float be0 = beta[c0], be1 = beta[c1];
  float w200 = W2[c0 * 2], w201 = W2[c0 * 2 + 1];
  float w210 = W2[c1 * 2], w211 = W2[c1 * 2 + 1];
  const float* z = zbase + (size_t)g * NB * DF;
  float* mmd = mmd_base + (size_t)g * NB * DF;
  int rbase = blockIdx.x * 16 + w * 4;
  for (int rr = 0; rr < 4; ++rr){
    int row = rbase + rr;
    float2 zv = *(const float2*)(z + (size_t)row * DF + c0);
    float y0 = fmaxf((zv.x - m0) * is0 * ga0 + be0, 0.f);
    float y1 = fmaxf((zv.y - m1) * is1 * ga1 + be1, 0.f);
    float2 yv; yv.x = y0; yv.y = y1;
    *(float2*)(mmd + (size_t)row * DF + c0) = yv;
    if (g == 0){
      float s0 = y0 * w200 + y1 * w210;
      float s1 = y0 * w201 + y1 * w211;
      for (int o = 32; o > 0; o >>= 1){
        s0 += __shfl_xor(s0, o);
        s1 += __shfl_xor(s1, o);
      }
      if (l == 0){
        hp[row * 2]     = s0 + b2[0];
        hp[row * 2 + 1] = s1 + b2[1];
      }
    }
  }
}

extern "C" __attribute__((used, visibility("default")))
void kernel_launch(void* const* d_in, const int* in_sizes, int n_in,
                   void* d_out, int out_size, void* d_ws, size_t ws_size,
                   hipStream_t stream){
  const float* h_in  = (const float*)d_in[0];
  const int* esrc = (const int*)d_in[1];
  const int* edst = (const int*)d_in[2];
  const int* x1   = (const int*)d_in[3];
  const int* x2   = (const int*)d_in[4];
  const int* x1t  = (const int*)d_in[5];
  const int* x2t  = (const int*)d_in[6];
  const float* Wself = (const float*)d_in[7];
  const float* Wneigh= (const float*)d_in[8];
  const float* bconv = (const float*)d_in[9];
  const float* W1    = (const float*)d_in[10];
  const float* b1    = (const float*)d_in[11];
  const float* gamma = (const float*)d_in[12];
  const float* beta  = (const float*)d_in[13];
  const float* W2    = (const float*)d_in[14];
  const float* b2    = (const float*)d_in[15];
  float* out = (float*)d_out;                   // fp32 outputs
  float* hp_out   = out;                        // [NB,2]
  float* mmd_base = out + 2 * NB;               // [2][NB,DF] contiguous

  // ---- workspace layout (~45.8 MB) ----
  float* zreg  = (float*)d_ws;                       // 2*NB*DF f32 (src|tar)
  float* stats = zreg + (size_t)2 * NB * DF;         // 512
  float* mstd  = stats + 512;                        // 512 (layout pad)
  float* dinv  = mstd + 512;                         // 50,048
  int* cnt  = (int*)(dinv + 50048);                  // 50,000
  int* fill = cnt + NN;                              // 50,000
  int* rp   = fill + NN;                             // 50,016
  int* perm = rp + 50016;                            // 600,000
  int* bsum = perm + 600000;                         // 256
  unsigned short* h_c = (unsigned short*)(bsum + 256);    // NN*DF u16
  unsigned short* h1b = h_c + (size_t)NN * DF;            // NN*DF u16
  unsigned short* h2b = h_c;                 // alias: h_c dead after layer 0
  unsigned short* WsB = h1b + (size_t)NN * DF;  // 2*DF*DF u16 (both layers)
  unsigned short* WnB = WsB + 2 * DF * DF;      // 2*DF*DF u16
  unsigned short* W1B = WnB + 2 * DF * DF;      // 3*DF*DF u16

  // fused prelude: h cast + zeroing + weight swizzle
  k_prelude<<<3710, 256, 0, stream>>>(h_in, h_c, Wself, Wneigh, W1,
                                      WsB, WnB, W1B, cnt, stats);

  // CSR build (scan2 folded into scan3)
  k_hist<<<(NE + 255) / 256, 256, 0, stream>>>(edst, cnt);
  k_scan1<<<196, 256, 0, stream>>>(cnt, bsum);
  k_scan3<<<196, 256, 0, stream>>>(cnt, bsum, rp, dinv);
  k_scatter<<<(NE + 255) / 256, 256, 0, stream>>>(esrc, edst, rp, fill, perm);

  // SAGE layer 0 (fused agg+GEMM): h_c -> h1b
  k_layer_mfma<<<(NN + 63) / 64, 256, 0, stream>>>(h_c, rp, perm, dinv,
                                                   WsB, WnB, bconv, h1b);
  // SAGE layer 1 (fused agg+GEMM): h1b -> h2b
  k_layer_mfma<<<(NN + 63) / 64, 256, 0, stream>>>(h1b, rp, perm, dinv,
                                                   WsB + DF * DF, WnB + DF * DF,
                                                   bconv + DF, h2b);

  // head: pair GEMM (+ fused col-stats), then normalize (+ fused h_p)
  k_pair_mfma<<<dim3(NB / 64, 2), 256, 0, stream>>>(h2b, x1, x2, x1t, x2t,
                                                    W1B, b1, zreg, stats);
  k_norm_hp<<<dim3(NB / 16, 2), 256, 0, stream>>>(zreg, stats, gamma, beta,
                                                  W2, b2, mmd_base, hp_out);
}

// Round 7
// 295.555 us; speedup vs baseline: 1.1622x; 1.1622x over previous
//
#include <hip/hip_runtime.h>

#define NN 50000   // nodes
#define NE 600000  // edges
#define DF 128     // features
#define NB 16384   // pair batch

typedef short bf16x8 __attribute__((ext_vector_type(8)));
typedef float f32x4 __attribute__((ext_vector_type(4)));

__device__ __forceinline__ float bf2f(unsigned short u){
  return __uint_as_float(((unsigned int)u) << 16);
}
__device__ __forceinline__ unsigned short f2bf(float x){
  unsigned int b = __float_as_uint(x);
  return (unsigned short)((b + 0x7FFFu + ((b >> 16) & 1u)) >> 16);
}

// Original template symbol (defined, never launched).
__global__ void GraphSAGE_8504035246140_kernel(){ }

// ---- fused prelude: h cast | zero cnt/fill | zero stats | weight swizzle ----
__global__ __launch_bounds__(256) void k_prelude(
    const float* h_in, unsigned short* h_c,
    const float* Ws, const float* Wn, const float* W1,
    unsigned short* WsB, unsigned short* WnB, unsigned short* W1B,
    int* cnt, float* stats){
  int b = blockIdx.x, t = threadIdx.x;
  if (b < 3125){                       // 3125*256 == NN*DF/8 exactly
    int i = b * 256 + t;
    const float4* s = (const float4*)h_in;
    float4 v0 = s[i * 2], v1 = s[i * 2 + 1];
    unsigned short d[8] = {f2bf(v0.x), f2bf(v0.y), f2bf(v0.z), f2bf(v0.w),
                           f2bf(v1.x), f2bf(v1.y), f2bf(v1.z), f2bf(v1.w)};
    *(bf16x8*)(h_c + i * 8) = *(bf16x8*)d;
  } else if (b < 3516){
    int i = (b - 3125) * 256 + t;
    if (i < 2 * NN) cnt[i] = 0;        // cnt + fill (adjacent)
  } else if (b < 3518){
    int i = (b - 3516) * 256 + t;
    if (i < 512) stats[i] = 0.f;
  } else {
    int idx = (b - 3518) * 256 + t;    // 192 blocks -> 49152 threads
    if (idx < 2 * DF * DF){
      int layer = idx >> 14;
      int e = idx & (DF * DF - 1);
      int k = e >> 7, n = e & 127;
      int dst = layer * DF * DF + (((k >> 3) * 128 + n) << 3) + (k & 7);
      WsB[dst] = f2bf(Ws[idx]);
      WnB[dst] = f2bf(Wn[idx]);
    }
    if (idx < 3 * DF * DF){
      int k = idx >> 7, n = idx & 127; // W1: 384x128
      W1B[(((k >> 3) * 128 + n) << 3) + (k & 7)] = f2bf(W1[idx]);
    }
  }
}

// ---- CSR build ----
__global__ void k_hist(const int* dst, int* cnt){
  int e = blockIdx.x * 256 + threadIdx.x;
  if (e < NE) atomicAdd(&cnt[dst[e]], 1);
}
__global__ void k_scan1(const int* cnt, int* bsum){   // grid 196: block sums
  __shared__ int l[256];
  int t = threadIdx.x, i = blockIdx.x * 256 + t;
  l[t] = (i < NN) ? cnt[i] : 0;
  __syncthreads();
  for (int o = 128; o > 0; o >>= 1){
    if (t < o) l[t] += l[t + o];
    __syncthreads();
  }
  if (t == 0) bsum[blockIdx.x] = l[0];
}
// scan3: folds the global scan of bsum (196 values) into every block.
__global__ void k_scan3(const int* cnt, const int* bsum, int* rp){
  __shared__ int bs[256];
  __shared__ int l[256];
  int t = threadIdx.x, i = blockIdx.x * 256 + t;
  bs[t] = (t < 196) ? bsum[t] : 0;
  int v = (i < NN) ? cnt[i] : 0;
  l[t] = v;
  __syncthreads();
  for (int o = 1; o < 256; o <<= 1){
    int xb = (t >= o) ? bs[t - o] : 0;
    int xl = (t >= o) ? l[t - o] : 0;
    __syncthreads();
    bs[t] += xb; l[t] += xl;
    __syncthreads();
  }
  int base = (blockIdx.x == 0) ? 0 : bs[blockIdx.x - 1];
  if (i < NN){
    rp[i] = base + l[t] - v;
    if (i == NN - 1) rp[NN] = base + l[t];
  }
}
__global__ void k_scatter(const int* src, const int* dst,
                          const int* rp, int* fill, int* perm){
  int e = blockIdx.x * 256 + threadIdx.x;
  if (e < NE){
    int d = dst[e];
    int pos = atomicAdd(&fill[d], 1);
    perm[rp[d] + pos] = src[e];
  }
}

// ---- mean aggregation: one wave per node, uint4 gather, 32-edge batch ----
// 16 lanes x 16B cover one 256B row -> 4 edge-rows per wave-load; 8 loads in
// flight = 32 edges per batch. Poisson(12) degrees => ~99.99% of nodes finish
// in ONE predicated batch (OOB slots clamp to perm[s]; their sums are
// predicated off). deg>32 falls to the 32-edge main loop. Cross-slot combine
// via shfl_xor(16)+shfl_xor(32); lanes rs==0 pack+store one uint4 each.
// dinv removed: di = 1/max(deg,1) computed from the row pointers (same math
// as the reference's clamped mean; drops a dependent global load).
__global__ __launch_bounds__(256) void k_agg(
    const unsigned int* hb32, const int* rp, const int* perm,
    unsigned int* agg32){
  int n = blockIdx.x * 4 + (threadIdx.x >> 6);
  if (n >= NN) return;
  int l = threadIdx.x & 63;
  int rs = l >> 4, li = l & 15;        // row slot 0..3, 16B chunk 0..15
  int s = rp[n], e = rp[n + 1];
  const unsigned int* hq = hb32 + li * 4;
  float a0 = 0.f, a1 = 0.f, a2 = 0.f, a3 = 0.f;
  float a4 = 0.f, a5 = 0.f, a6 = 0.f, a7 = 0.f;
  int i = s;
  for (; i + 32 <= e; i += 32){
    int p0 = perm[i + rs];
    int p1 = perm[i + 4 + rs];
    int p2 = perm[i + 8 + rs];
    int p3 = perm[i + 12 + rs];
    int p4 = perm[i + 16 + rs];
    int p5 = perm[i + 20 + rs];
    int p6 = perm[i + 24 + rs];
    int p7 = perm[i + 28 + rs];
    uint4 x0 = *(const uint4*)(hq + (size_t)p0 * 64);
    uint4 x1 = *(const uint4*)(hq + (size_t)p1 * 64);
    uint4 x2 = *(const uint4*)(hq + (size_t)p2 * 64);
    uint4 x3 = *(const uint4*)(hq + (size_t)p3 * 64);
    uint4 x4 = *(const uint4*)(hq + (size_t)p4 * 64);
    uint4 x5 = *(const uint4*)(hq + (size_t)p5 * 64);
    uint4 x6 = *(const uint4*)(hq + (size_t)p6 * 64);
    uint4 x7 = *(const uint4*)(hq + (size_t)p7 * 64);
    a0 += __uint_as_float(x0.x << 16); a1 += __uint_as_float(x0.x & 0xffff0000u);
    a2 += __uint_as_float(x0.y << 16); a3 += __uint_as_float(x0.y & 0xffff0000u);
    a4 += __uint_as_float(x0.z << 16); a5 += __uint_as_float(x0.z & 0xffff0000u);
    a6 += __uint_as_float(x0.w << 16); a7 += __uint_as_float(x0.w & 0xffff0000u);
    a0 += __uint_as_float(x1.x << 16); a1 += __uint_as_float(x1.x & 0xffff0000u);
    a2 += __uint_as_float(x1.y << 16); a3 += __uint_as_float(x1.y & 0xffff0000u);
    a4 += __uint_as_float(x1.z << 16); a5 += __uint_as_float(x1.z & 0xffff0000u);
    a6 += __uint_as_float(x1.w << 16); a7 += __uint_as_float(x1.w & 0xffff0000u);
    a0 += __uint_as_float(x2.x << 16); a1 += __uint_as_float(x2.x & 0xffff0000u);
    a2 += __uint_as_float(x2.y << 16); a3 += __uint_as_float(x2.y & 0xffff0000u);
    a4 += __uint_as_float(x2.z << 16); a5 += __uint_as_float(x2.z & 0xffff0000u);
    a6 += __uint_as_float(x2.w << 16); a7 += __uint_as_float(x2.w & 0xffff0000u);
    a0 += __uint_as_float(x3.x << 16); a1 += __uint_as_float(x3.x & 0xffff0000u);
    a2 += __uint_as_float(x3.y << 16); a3 += __uint_as_float(x3.y & 0xffff0000u);
    a4 += __uint_as_float(x3.z << 16); a5 += __uint_as_float(x3.z & 0xffff0000u);
    a6 += __uint_as_float(x3.w << 16); a7 += __uint_as_float(x3.w & 0xffff0000u);
    a0 += __uint_as_float(x4.x << 16); a1 += __uint_as_float(x4.x & 0xffff0000u);
    a2 += __uint_as_float(x4.y << 16); a3 += __uint_as_float(x4.y & 0xffff0000u);
    a4 += __uint_as_float(x4.z << 16); a5 += __uint_as_float(x4.z & 0xffff0000u);
    a6 += __uint_as_float(x4.w << 16); a7 += __uint_as_float(x4.w & 0xffff0000u);
    a0 += __uint_as_float(x5.x << 16); a1 += __uint_as_float(x5.x & 0xffff0000u);
    a2 += __uint_as_float(x5.y << 16); a3 += __uint_as_float(x5.y & 0xffff0000u);
    a4 += __uint_as_float(x5.z << 16); a5 += __uint_as_float(x5.z & 0xffff0000u);
    a6 += __uint_as_float(x5.w << 16); a7 += __uint_as_float(x5.w & 0xffff0000u);
    a0 += __uint_as_float(x6.x << 16); a1 += __uint_as_float(x6.x & 0xffff0000u);
    a2 += __uint_as_float(x6.y << 16); a3 += __uint_as_float(x6.y & 0xffff0000u);
    a4 += __uint_as_float(x6.z << 16); a5 += __uint_as_float(x6.z & 0xffff0000u);
    a6 += __uint_as_float(x6.w << 16); a7 += __uint_as_float(x6.w & 0xffff0000u);
    a0 += __uint_as_float(x7.x << 16); a1 += __uint_as_float(x7.x & 0xffff0000u);
    a2 += __uint_as_float(x7.y << 16); a3 += __uint_as_float(x7.y & 0xffff0000u);
    a4 += __uint_as_float(x7.z << 16); a5 += __uint_as_float(x7.z & 0xffff0000u);
    a6 += __uint_as_float(x7.w << 16); a7 += __uint_as_float(x7.w & 0xffff0000u);
  }
  if (i < e){
    int i0 = i + rs,      i1 = i + 4 + rs,  i2 = i + 8 + rs,  i3 = i + 12 + rs;
    int i4 = i + 16 + rs, i5 = i + 20 + rs, i6 = i + 24 + rs, i7 = i + 28 + rs;
    int p0 = perm[i0 < e ? i0 : s];
    int p1 = perm[i1 < e ? i1 : s];
    int p2 = perm[i2 < e ? i2 : s];
    int p3 = perm[i3 < e ? i3 : s];
    int p4 = perm[i4 < e ? i4 : s];
    int p5 = perm[i5 < e ? i5 : s];
    int p6 = perm[i6 < e ? i6 : s];
    int p7 = perm[i7 < e ? i7 : s];
    uint4 x0 = *(const uint4*)(hq + (size_t)p0 * 64);
    uint4 x1 = *(const uint4*)(hq + (size_t)p1 * 64);
    uint4 x2 = *(const uint4*)(hq + (size_t)p2 * 64);
    uint4 x3 = *(const uint4*)(hq + (size_t)p3 * 64);
    uint4 x4 = *(const uint4*)(hq + (size_t)p4 * 64);
    uint4 x5 = *(const uint4*)(hq + (size_t)p5 * 64);
    uint4 x6 = *(const uint4*)(hq + (size_t)p6 * 64);
    uint4 x7 = *(const uint4*)(hq + (size_t)p7 * 64);
    if (i0 < e){
      a0 += __uint_as_float(x0.x << 16); a1 += __uint_as_float(x0.x & 0xffff0000u);
      a2 += __uint_as_float(x0.y << 16); a3 += __uint_as_float(x0.y & 0xffff0000u);
      a4 += __uint_as_float(x0.z << 16); a5 += __uint_as_float(x0.z & 0xffff0000u);
      a6 += __uint_as_float(x0.w << 16); a7 += __uint_as_float(x0.w & 0xffff0000u);
    }
    if (i1 < e){
      a0 += __uint_as_float(x1.x << 16); a1 += __uint_as_float(x1.x & 0xffff0000u);
      a2 += __uint_as_float(x1.y << 16); a3 += __uint_as_float(x1.y & 0xffff0000u);
      a4 += __uint_as_float(x1.z << 16); a5 += __uint_as_float(x1.z & 0xffff0000u);
      a6 += __uint_as_float(x1.w << 16); a7 += __uint_as_float(x1.w & 0xffff0000u);
    }
    if (i2 < e){
      a0 += __uint_as_float(x2.x << 16); a1 += __uint_as_float(x2.x & 0xffff0000u);
      a2 += __uint_as_float(x2.y << 16); a3 += __uint_as_float(x2.y & 0xffff0000u);
      a4 += __uint_as_float(x2.z << 16); a5 += __uint_as_float(x2.z & 0xffff0000u);
      a6 += __uint_as_float(x2.w << 16); a7 += __uint_as_float(x2.w & 0xffff0000u);
    }
    if (i3 < e){
      a0 += __uint_as_float(x3.x << 16); a1 += __uint_as_float(x3.x & 0xffff0000u);
      a2 += __uint_as_float(x3.y << 16); a3 += __uint_as_float(x3.y & 0xffff0000u);
      a4 += __uint_as_float(x3.z << 16); a5 += __uint_as_float(x3.z & 0xffff0000u);
      a6 += __uint_as_float(x3.w << 16); a7 += __uint_as_float(x3.w & 0xffff0000u);
    }
    if (i4 < e){
      a0 += __uint_as_float(x4.x << 16); a1 += __uint_as_float(x4.x & 0xffff0000u);
      a2 += __uint_as_float(x4.y << 16); a3 += __uint_as_float(x4.y & 0xffff0000u);
      a4 += __uint_as_float(x4.z << 16); a5 += __uint_as_float(x4.z & 0xffff0000u);
      a6 += __uint_as_float(x4.w << 16); a7 += __uint_as_float(x4.w & 0xffff0000u);
    }
    if (i5 < e){
      a0 += __uint_as_float(x5.x << 16); a1 += __uint_as_float(x5.x & 0xffff0000u);
      a2 += __uint_as_float(x5.y << 16); a3 += __uint_as_float(x5.y & 0xffff0000u);
      a4 += __uint_as_float(x5.z << 16); a5 += __uint_as_float(x5.z & 0xffff0000u);
      a6 += __uint_as_float(x5.w << 16); a7 += __uint_as_float(x5.w & 0xffff0000u);
    }
    if (i6 < e){
      a0 += __uint_as_float(x6.x << 16); a1 += __uint_as_float(x6.x & 0xffff0000u);
      a2 += __uint_as_float(x6.y << 16); a3 += __uint_as_float(x6.y & 0xffff0000u);
      a4 += __uint_as_float(x6.z << 16); a5 += __uint_as_float(x6.z & 0xffff0000u);
      a6 += __uint_as_float(x6.w << 16); a7 += __uint_as_float(x6.w & 0xffff0000u);
    }
    if (i7 < e){
      a0 += __uint_as_float(x7.x << 16); a1 += __uint_as_float(x7.x & 0xffff0000u);
      a2 += __uint_as_float(x7.y << 16); a3 += __uint_as_float(x7.y & 0xffff0000u);
      a4 += __uint_as_float(x7.z << 16); a5 += __uint_as_float(x7.z & 0xffff0000u);
      a6 += __uint_as_float(x7.w << 16); a7 += __uint_as_float(x7.w & 0xffff0000u);
    }
  }
  a0 += __shfl_xor(a0, 16); a1 += __shfl_xor(a1, 16);
  a2 += __shfl_xor(a2, 16); a3 += __shfl_xor(a3, 16);
  a4 += __shfl_xor(a4, 16); a5 += __shfl_xor(a5, 16);
  a6 += __shfl_xor(a6, 16); a7 += __shfl_xor(a7, 16);
  a0 += __shfl_xor(a0, 32); a1 += __shfl_xor(a1, 32);
  a2 += __shfl_xor(a2, 32); a3 += __shfl_xor(a3, 32);
  a4 += __shfl_xor(a4, 32); a5 += __shfl_xor(a5, 32);
  a6 += __shfl_xor(a6, 32); a7 += __shfl_xor(a7, 32);
  if (rs == 0){
    float di = 1.0f / fmaxf((float)(e - s), 1.0f);
    uint4 r;
    r.x = (unsigned int)f2bf(a0 * di) | ((unsigned int)f2bf(a1 * di) << 16);
    r.y = (unsigned int)f2bf(a2 * di) | ((unsigned int)f2bf(a3 * di) << 16);
    r.z = (unsigned int)f2bf(a4 * di) | ((unsigned int)f2bf(a5 * di) << 16);
    r.w = (unsigned int)f2bf(a6 * di) | ((unsigned int)f2bf(a7 * di) << 16);
    *(uint4*)(agg32 + (size_t)n * 64 + li * 4) = r;
  }
}

// ---- layer GEMM via MFMA: hout = relu(h@Ws + agg@Wn + b) ----
__global__ __launch_bounds__(256) void k_layer_mfma(
    const unsigned short* hb, const unsigned short* aggb,
    const unsigned short* WsB, const unsigned short* WnB,
    const float* bias, unsigned short* hout){
  int t = threadIdx.x;
  int w = t >> 6, l = t & 63;
  int m = l & 15, q = l >> 4;
  int r0 = blockIdx.x * 64 + w * 16;
  int arow = r0 + m; if (arow > NN - 1) arow = NN - 1;
  const unsigned short* hp = hb   + (size_t)arow * DF + q * 8;
  const unsigned short* ap = aggb + (size_t)arow * DF + q * 8;
  f32x4 acc[8];
  for (int ct = 0; ct < 8; ++ct){
    float bbc = bias[ct * 16 + m];
    acc[ct] = (f32x4){bbc, bbc, bbc, bbc};
  }
  for (int kt = 0; kt < 4; ++kt){
    bf16x8 a_h = *(const bf16x8*)(hp + kt * 32);
    bf16x8 a_g = *(const bf16x8*)(ap + kt * 32);
    int kg = kt * 4 + q;
    for (int ct = 0; ct < 8; ++ct){
      bf16x8 b_s = *(const bf16x8*)(WsB + (((kg << 7) + ct * 16 + m) << 3));
      bf16x8 b_n = *(const bf16x8*)(WnB + (((kg << 7) + ct * 16 + m) << 3));
      acc[ct] = __builtin_amdgcn_mfma_f32_16x16x32_bf16(a_h, b_s, acc[ct], 0, 0, 0);
      acc[ct] = __builtin_amdgcn_mfma_f32_16x16x32_bf16(a_g, b_n, acc[ct], 0, 0, 0);
    }
  }
  for (int ct = 0; ct < 8; ++ct){
    int col = ct * 16 + m;
    for (int reg = 0; reg < 4; ++reg){
      int row = r0 + q * 4 + reg;
      if (row < NN) hout[(size_t)row * DF + col] = f2bf(fmaxf(acc[ct][reg], 0.f));
    }
  }
}

// ---- pair GEMM via MFMA + fused BN column stats; src/tar via blockIdx.y ----
__global__ __launch_bounds__(256) void k_pair_mfma(
    const unsigned short* h2,
    const int* x1, const int* x2, const int* x1t, const int* x2t,
    const unsigned short* W1B, const float* b1, float* zbase, float* stats){
  __shared__ __align__(16) unsigned short F[64 * 392];
  __shared__ float csum[128], csq[128];
  int g = blockIdx.y;
  const int* ia = g ? x1t : x1;
  const int* ib = g ? x2t : x2;
  float* z = zbase + (size_t)g * NB * DF;
  int t = threadIdx.x;
  if (t < 128){ csum[t] = 0.f; csq[t] = 0.f; }
  int r0 = blockIdx.x * 64;
  int i = t >> 2, qq = t & 3;
  int r = r0 + i;
  int a = ia[r], b = ib[r];
  const unsigned short* pa = h2 + (size_t)a * DF + qq * 32;
  const unsigned short* pb = h2 + (size_t)b * DF + qq * 32;
  unsigned short* fr = F + i * 392;
  for (int jj = 0; jj < 4; ++jj){
    bf16x8 va = *(const bf16x8*)(pa + jj * 8);
    bf16x8 vb = *(const bf16x8*)(pb + jj * 8);
    *(bf16x8*)(fr + qq * 32 + jj * 8) = va;
    *(bf16x8*)(fr + 128 + qq * 32 + jj * 8) = vb;
    unsigned short d[8];
    for (int e = 0; e < 8; ++e){
      float fa = bf2f((unsigned short)va[e]);
      float fb = bf2f((unsigned short)vb[e]);
      d[e] = f2bf(fabsf(fa - fb));
    }
    *(bf16x8*)(fr + 256 + qq * 32 + jj * 8) = *(bf16x8*)d;
  }
  __syncthreads();
  int w = t >> 6, l = t & 63;
  int m = l & 15, q = l >> 4;
  int rl = w * 16 + m;
  f32x4 acc[8];
  for (int ct = 0; ct < 8; ++ct){
    float bbc = b1[ct * 16 + m];
    acc[ct] = (f32x4){bbc, bbc, bbc, bbc};
  }
  for (int kt = 0; kt < 12; ++kt){
    bf16x8 af = *(const bf16x8*)(F + rl * 392 + kt * 32 + q * 8);
    int kg = kt * 4 + q;
    for (int ct = 0; ct < 8; ++ct){
      bf16x8 bfr = *(const bf16x8*)(W1B + (((kg << 7) + ct * 16 + m) << 3));
      acc[ct] = __builtin_amdgcn_mfma_f32_16x16x32_bf16(af, bfr, acc[ct], 0, 0, 0);
    }
  }
  for (int ct = 0; ct < 8; ++ct){
    int col = ct * 16 + m;
    int row = r0 + w * 16 + q * 4;
    float s = 0.f, s2 = 0.f;
    for (int reg = 0; reg < 4; ++reg){
      float v = acc[ct][reg];
      z[(size_t)(row + reg) * DF + col] = v;
      s += v; s2 += v * v;
    }
    atomicAdd(&csum[col], s);
    atomicAdd(&csq[col], s2);
  }
  __syncthreads();
  if (t < 128){
    atomicAdd(&stats[g * 256 + t], csum[t]);
    atomicAdd(&stats[g * 256 + 128 + t], csq[t]);
  }
}

// ---- fused BN-normalize + relu + (src only) h_p GEMM, barrier-free ----
// One wave per 4 rows; 2 columns per lane; h_p dot via shfl_xor reduction.
__global__ __launch_bounds__(256) void k_norm_hp(
    const float* zbase, const float* stats,
    const float* gamma, const float* beta,
    const float* W2, const float* b2, float* mmd_base, float* hp){
  int g = blockIdx.y;
  int t = threadIdx.x;
  int w = t >> 6, l = t & 63;
  int c0 = l * 2, c1 = c0 + 1;
  float m0 = stats[g * 256 + c0] * (1.0f / NB);
  float m1 = stats[g * 256 + c1] * (1.0f / NB);
  float v0 = stats[g * 256 + 128 + c0] * (1.0f / NB) - m0 * m0;
  float v1 = stats[g * 256 + 128 + c1] * (1.0f / NB) - m1 * m1;
  float is0 = 1.0f / sqrtf(v0 + 1e-5f);
  float is1 = 1.0f / sqrtf(v1 + 1e-5f);
  float ga0 = gamma[c0], ga1 = gamma[c1];
  float be0 = beta[c0], be1 = beta[c1];
  float w200 = W2[c0 * 2], w201 = W2[c0 * 2 + 1];
  float w210 = W2[c1 * 2], w211 = W2[c1 * 2 + 1];
  const float* z = zbase + (size_t)g * NB * DF;
  float* mmd = mmd_base + (size_t)g * NB * DF;
  int rbase = blockIdx.x * 16 + w * 4;
  for (int rr = 0; rr < 4; ++rr){
    int row = rbase + rr;
    float2 zv = *(const float2*)(z + (size_t)row * DF + c0);
    float y0 = fmaxf((zv.x - m0) * is0 * ga0 + be0, 0.f);
    float y1 = fmaxf((zv.y - m1) * is1 * ga1 + be1, 0.f);
    float2 yv; yv.x = y0; yv.y = y1;
    *(float2*)(mmd + (size_t)row * DF + c0) = yv;
    if (g == 0){
      float s0 = y0 * w200 + y1 * w210;
      float s1 = y0 * w201 + y1 * w211;
      for (int o = 32; o > 0; o >>= 1){
        s0 += __shfl_xor(s0, o);
        s1 += __shfl_xor(s1, o);
      }
      if (l == 0){
        hp[row * 2]     = s0 + b2[0];
        hp[row * 2 + 1] = s1 + b2[1];
      }
    }
  }
}

extern "C" __attribute__((used, visibility("default")))
void kernel_launch(void* const* d_in, const int* in_sizes, int n_in,
                   void* d_out, int out_size, void* d_ws, size_t ws_size,
                   hipStream_t stream){
  const float* h_in  = (const float*)d_in[0];
  const int* esrc = (const int*)d_in[1];
  const int* edst = (const int*)d_in[2];
  const int* x1   = (const int*)d_in[3];
  const int* x2   = (const int*)d_in[4];
  const int* x1t  = (const int*)d_in[5];
  const int* x2t  = (const int*)d_in[6];
  const float* Wself = (const float*)d_in[7];
  const float* Wneigh= (const float*)d_in[8];
  const float* bconv = (const float*)d_in[9];
  const float* W1    = (const float*)d_in[10];
  const float* b1    = (const float*)d_in[11];
  const float* gamma = (const float*)d_in[12];
  const float* beta  = (const float*)d_in[13];
  const float* W2    = (const float*)d_in[14];
  const float* b2    = (const float*)d_in[15];
  float* out = (float*)d_out;                   // fp32 outputs
  float* hp_out   = out;                        // [NB,2]
  float* mmd_base = out + 2 * NB;               // [2][NB,DF] contiguous

  // ---- workspace layout (~45.8 MB) ----
  float* zreg  = (float*)d_ws;                       // 2*NB*DF f32 (src|tar)
  unsigned short* aggb = (unsigned short*)zreg;      // alias (dead before z)
  float* stats = zreg + (size_t)2 * NB * DF;         // 512
  float* mstd  = stats + 512;                        // 512 (layout pad)
  float* dinv  = mstd + 512;                         // 50,048 (unused slot)
  int* cnt  = (int*)(dinv + 50048);                  // 50,000
  int* fill = cnt + NN;                              // 50,000
  int* rp   = fill + NN;                             // 50,016
  int* perm = rp + 50016;                            // 600,000
  int* bsum = perm + 600000;                         // 256
  unsigned short* h_c = (unsigned short*)(bsum + 256);    // NN*DF u16
  unsigned short* h1b = h_c + (size_t)NN * DF;            // NN*DF u16
  unsigned short* h2b = h_c;                 // alias: h_c dead after layer 0
  unsigned short* WsB = h1b + (size_t)NN * DF;  // 2*DF*DF u16 (both layers)
  unsigned short* WnB = WsB + 2 * DF * DF;      // 2*DF*DF u16
  unsigned short* W1B = WnB + 2 * DF * DF;      // 3*DF*DF u16
  (void)dinv;

  // fused prelude: h cast + zeroing + weight swizzle
  k_prelude<<<3710, 256, 0, stream>>>(h_in, h_c, Wself, Wneigh, W1,
                                      WsB, WnB, W1B, cnt, stats);

  // CSR build (scan2 folded into scan3)
  k_hist<<<(NE + 255) / 256, 256, 0, stream>>>(edst, cnt);
  k_scan1<<<196, 256, 0, stream>>>(cnt, bsum);
  k_scan3<<<196, 256, 0, stream>>>(cnt, bsum, rp);
  k_scatter<<<(NE + 255) / 256, 256, 0, stream>>>(esrc, edst, rp, fill, perm);

  // SAGE layer 0: h_c -> h1b
  k_agg<<<(NN + 3) / 4, 256, 0, stream>>>((const unsigned int*)h_c, rp, perm,
                                          (unsigned int*)aggb);
  k_layer_mfma<<<(NN + 63) / 64, 256, 0, stream>>>(h_c, aggb, WsB, WnB, bconv, h1b);
  // SAGE layer 1: h1b -> h2b
  k_agg<<<(NN + 3) / 4, 256, 0, stream>>>((const unsigned int*)h1b, rp, perm,
                                          (unsigned int*)aggb);
  k_layer_mfma<<<(NN + 63) / 64, 256, 0, stream>>>(h1b, aggb, WsB + DF * DF,
                                                   WnB + DF * DF, bconv + DF, h2b);

  // head: pair GEMM (+ fused col-stats), then normalize (+ fused h_p)
  k_pair_mfma<<<dim3(NB / 64, 2), 256, 0, stream>>>(h2b, x1, x2, x1t, x2t,
                                                    W1B, b1, zreg, stats);
  k_norm_hp<<<dim3(NB / 16, 2), 256, 0, stream>>>(zreg, stats, gamma, beta,
                                                  W2, b2, mmd_base, hp_out);
}

// Round 8
// 279.786 us; speedup vs baseline: 1.2277x; 1.0564x over previous
//
#include <hip/hip_runtime.h>

#define NN 50000   // nodes
#define NE 600000  // edges
#define DF 128     // features
#define NB 16384   // pair batch

typedef short bf16x8 __attribute__((ext_vector_type(8)));
typedef float f32x4 __attribute__((ext_vector_type(4)));

__device__ __forceinline__ float bf2f(unsigned short u){
  return __uint_as_float(((unsigned int)u) << 16);
}
__device__ __forceinline__ unsigned short f2bf(float x){
  unsigned int b = __float_as_uint(x);
  return (unsigned short)((b + 0x7FFFu + ((b >> 16) & 1u)) >> 16);
}

// Original template symbol (defined, never launched).
__global__ void GraphSAGE_8504035246140_kernel(){ }

// ---- fused prelude: h cast | zero cnt/fill | zero stats | weight swizzle ----
__global__ __launch_bounds__(256) void k_prelude(
    const float* h_in, unsigned short* h_c,
    const float* Ws, const float* Wn, const float* W1,
    unsigned short* WsB, unsigned short* WnB, unsigned short* W1B,
    int* cnt, float* stats){
  int b = blockIdx.x, t = threadIdx.x;
  if (b < 3125){                       // 3125*256 == NN*DF/8 exactly
    int i = b * 256 + t;
    const float4* s = (const float4*)h_in;
    float4 v0 = s[i * 2], v1 = s[i * 2 + 1];
    unsigned short d[8] = {f2bf(v0.x), f2bf(v0.y), f2bf(v0.z), f2bf(v0.w),
                           f2bf(v1.x), f2bf(v1.y), f2bf(v1.z), f2bf(v1.w)};
    *(bf16x8*)(h_c + i * 8) = *(bf16x8*)d;
  } else if (b < 3516){
    int i = (b - 3125) * 256 + t;
    if (i < 2 * NN) cnt[i] = 0;        // cnt + fill (adjacent)
  } else if (b < 3518){
    int i = (b - 3516) * 256 + t;
    if (i < 512) stats[i] = 0.f;
  } else {
    int idx = (b - 3518) * 256 + t;    // 192 blocks -> 49152 threads
    if (idx < 2 * DF * DF){
      int layer = idx >> 14;
      int e = idx & (DF * DF - 1);
      int k = e >> 7, n = e & 127;
      int dst = layer * DF * DF + (((k >> 3) * 128 + n) << 3) + (k & 7);
      WsB[dst] = f2bf(Ws[idx]);
      WnB[dst] = f2bf(Wn[idx]);
    }
    if (idx < 3 * DF * DF){
      int k = idx >> 7, n = idx & 127; // W1: 384x128
      W1B[(((k >> 3) * 128 + n) << 3) + (k & 7)] = f2bf(W1[idx]);
    }
  }
}

// ---- CSR build ----
__global__ void k_hist(const int* dst, int* cnt){
  int e = blockIdx.x * 256 + threadIdx.x;
  if (e < NE) atomicAdd(&cnt[dst[e]], 1);
}
__global__ void k_scan1(const int* cnt, int* bsum){   // grid 196: block sums
  __shared__ int l[256];
  int t = threadIdx.x, i = blockIdx.x * 256 + t;
  l[t] = (i < NN) ? cnt[i] : 0;
  __syncthreads();
  for (int o = 128; o > 0; o >>= 1){
    if (t < o) l[t] += l[t + o];
    __syncthreads();
  }
  if (t == 0) bsum[blockIdx.x] = l[0];
}
// scan3: folds the global scan of bsum (196 values) into every block.
__global__ void k_scan3(const int* cnt, const int* bsum, int* rp){
  __shared__ int bs[256];
  __shared__ int l[256];
  int t = threadIdx.x, i = blockIdx.x * 256 + t;
  bs[t] = (t < 196) ? bsum[t] : 0;
  int v = (i < NN) ? cnt[i] : 0;
  l[t] = v;
  __syncthreads();
  for (int o = 1; o < 256; o <<= 1){
    int xb = (t >= o) ? bs[t - o] : 0;
    int xl = (t >= o) ? l[t - o] : 0;
    __syncthreads();
    bs[t] += xb; l[t] += xl;
    __syncthreads();
  }
  int base = (blockIdx.x == 0) ? 0 : bs[blockIdx.x - 1];
  if (i < NN){
    rp[i] = base + l[t] - v;
    if (i == NN - 1) rp[NN] = base + l[t];
  }
}
__global__ void k_scatter(const int* src, const int* dst,
                          const int* rp, int* fill, int* perm){
  int e = blockIdx.x * 256 + threadIdx.x;
  if (e < NE){
    int d = dst[e];
    int pos = atomicAdd(&fill[d], 1);
    perm[rp[d] + pos] = src[e];
  }
}

// ---- mean aggregation: one wave per node, uint4 gather, 16-edge batch ----
// (r5 structure: the measured best. 32-edge batching regressed — clamped
// duplicate loads burn request slots for the ~90% of nodes with deg<=16.)
// 16 lanes x 16B cover one 256B row -> 4 edge-rows per wave-load; 4 loads in
// flight = 16 edges per batch; tail is one predicated batch. Cross-slot
// combine via shfl_xor(16,32). di computed from row pointers (no dinv load).
__global__ __launch_bounds__(256) void k_agg(
    const unsigned int* hb32, const int* rp, const int* perm,
    unsigned int* agg32){
  int n = blockIdx.x * 4 + (threadIdx.x >> 6);
  if (n >= NN) return;
  int l = threadIdx.x & 63;
  int rs = l >> 4, li = l & 15;        // row slot 0..3, 16B chunk 0..15
  int s = rp[n], e = rp[n + 1];
  const unsigned int* hq = hb32 + li * 4;
  float a0 = 0.f, a1 = 0.f, a2 = 0.f, a3 = 0.f;
  float a4 = 0.f, a5 = 0.f, a6 = 0.f, a7 = 0.f;
  int i = s;
  for (; i + 16 <= e; i += 16){
    int p0 = perm[i + rs];
    int p1 = perm[i + 4 + rs];
    int p2 = perm[i + 8 + rs];
    int p3 = perm[i + 12 + rs];
    uint4 x0 = *(const uint4*)(hq + (size_t)p0 * 64);
    uint4 x1 = *(const uint4*)(hq + (size_t)p1 * 64);
    uint4 x2 = *(const uint4*)(hq + (size_t)p2 * 64);
    uint4 x3 = *(const uint4*)(hq + (size_t)p3 * 64);
    a0 += __uint_as_float(x0.x << 16); a1 += __uint_as_float(x0.x & 0xffff0000u);
    a2 += __uint_as_float(x0.y << 16); a3 += __uint_as_float(x0.y & 0xffff0000u);
    a4 += __uint_as_float(x0.z << 16); a5 += __uint_as_float(x0.z & 0xffff0000u);
    a6 += __uint_as_float(x0.w << 16); a7 += __uint_as_float(x0.w & 0xffff0000u);
    a0 += __uint_as_float(x1.x << 16); a1 += __uint_as_float(x1.x & 0xffff0000u);
    a2 += __uint_as_float(x1.y << 16); a3 += __uint_as_float(x1.y & 0xffff0000u);
    a4 += __uint_as_float(x1.z << 16); a5 += __uint_as_float(x1.z & 0xffff0000u);
    a6 += __uint_as_float(x1.w << 16); a7 += __uint_as_float(x1.w & 0xffff0000u);
    a0 += __uint_as_float(x2.x << 16); a1 += __uint_as_float(x2.x & 0xffff0000u);
    a2 += __uint_as_float(x2.y << 16); a3 += __uint_as_float(x2.y & 0xffff0000u);
    a4 += __uint_as_float(x2.z << 16); a5 += __uint_as_float(x2.z & 0xffff0000u);
    a6 += __uint_as_float(x2.w << 16); a7 += __uint_as_float(x2.w & 0xffff0000u);
    a0 += __uint_as_float(x3.x << 16); a1 += __uint_as_float(x3.x & 0xffff0000u);
    a2 += __uint_as_float(x3.y << 16); a3 += __uint_as_float(x3.y & 0xffff0000u);
    a4 += __uint_as_float(x3.z << 16); a5 += __uint_as_float(x3.z & 0xffff0000u);
    a6 += __uint_as_float(x3.w << 16); a7 += __uint_as_float(x3.w & 0xffff0000u);
  }
  if (i < e){
    int i0 = i + rs, i1 = i + 4 + rs, i2 = i + 8 + rs, i3 = i + 12 + rs;
    int p0 = perm[i0 < e ? i0 : s];
    int p1 = perm[i1 < e ? i1 : s];
    int p2 = perm[i2 < e ? i2 : s];
    int p3 = perm[i3 < e ? i3 : s];
    uint4 x0 = *(const uint4*)(hq + (size_t)p0 * 64);
    uint4 x1 = *(const uint4*)(hq + (size_t)p1 * 64);
    uint4 x2 = *(const uint4*)(hq + (size_t)p2 * 64);
    uint4 x3 = *(const uint4*)(hq + (size_t)p3 * 64);
    if (i0 < e){
      a0 += __uint_as_float(x0.x << 16); a1 += __uint_as_float(x0.x & 0xffff0000u);
      a2 += __uint_as_float(x0.y << 16); a3 += __uint_as_float(x0.y & 0xffff0000u);
      a4 += __uint_as_float(x0.z << 16); a5 += __uint_as_float(x0.z & 0xffff0000u);
      a6 += __uint_as_float(x0.w << 16); a7 += __uint_as_float(x0.w & 0xffff0000u);
    }
    if (i1 < e){
      a0 += __uint_as_float(x1.x << 16); a1 += __uint_as_float(x1.x & 0xffff0000u);
      a2 += __uint_as_float(x1.y << 16); a3 += __uint_as_float(x1.y & 0xffff0000u);
      a4 += __uint_as_float(x1.z << 16); a5 += __uint_as_float(x1.z & 0xffff0000u);
      a6 += __uint_as_float(x1.w << 16); a7 += __uint_as_float(x1.w & 0xffff0000u);
    }
    if (i2 < e){
      a0 += __uint_as_float(x2.x << 16); a1 += __uint_as_float(x2.x & 0xffff0000u);
      a2 += __uint_as_float(x2.y << 16); a3 += __uint_as_float(x2.y & 0xffff0000u);
      a4 += __uint_as_float(x2.z << 16); a5 += __uint_as_float(x2.z & 0xffff0000u);
      a6 += __uint_as_float(x2.w << 16); a7 += __uint_as_float(x2.w & 0xffff0000u);
    }
    if (i3 < e){
      a0 += __uint_as_float(x3.x << 16); a1 += __uint_as_float(x3.x & 0xffff0000u);
      a2 += __uint_as_float(x3.y << 16); a3 += __uint_as_float(x3.y & 0xffff0000u);
      a4 += __uint_as_float(x3.z << 16); a5 += __uint_as_float(x3.z & 0xffff0000u);
      a6 += __uint_as_float(x3.w << 16); a7 += __uint_as_float(x3.w & 0xffff0000u);
    }
  }
  a0 += __shfl_xor(a0, 16); a1 += __shfl_xor(a1, 16);
  a2 += __shfl_xor(a2, 16); a3 += __shfl_xor(a3, 16);
  a4 += __shfl_xor(a4, 16); a5 += __shfl_xor(a5, 16);
  a6 += __shfl_xor(a6, 16); a7 += __shfl_xor(a7, 16);
  a0 += __shfl_xor(a0, 32); a1 += __shfl_xor(a1, 32);
  a2 += __shfl_xor(a2, 32); a3 += __shfl_xor(a3, 32);
  a4 += __shfl_xor(a4, 32); a5 += __shfl_xor(a5, 32);
  a6 += __shfl_xor(a6, 32); a7 += __shfl_xor(a7, 32);
  if (rs == 0){
    float di = 1.0f / fmaxf((float)(e - s), 1.0f);
    uint4 r;
    r.x = (unsigned int)f2bf(a0 * di) | ((unsigned int)f2bf(a1 * di) << 16);
    r.y = (unsigned int)f2bf(a2 * di) | ((unsigned int)f2bf(a3 * di) << 16);
    r.z = (unsigned int)f2bf(a4 * di) | ((unsigned int)f2bf(a5 * di) << 16);
    r.w = (unsigned int)f2bf(a6 * di) | ((unsigned int)f2bf(a7 * di) << 16);
    *(uint4*)(agg32 + (size_t)n * 64 + li * 4) = r;
  }
}

// ---- layer GEMM via MFMA, 2 row-tiles per wave ----
// hout = relu(h@Ws + agg@Wn + b). Each wave computes 32 rows (r and r+64):
// every weight fragment load now feeds 4 MFMAs instead of 2, halving the
// B-matrix L2 traffic (200MB -> 100MB across the dispatch) and per-row
// load-issue overhead. Block = 128 rows (4 waves x 2 tiles), grid 391.
__global__ __launch_bounds__(256) void k_layer_mfma(
    const unsigned short* hb, const unsigned short* aggb,
    const unsigned short* WsB, const unsigned short* WnB,
    const float* bias, unsigned short* hout){
  int t = threadIdx.x;
  int w = t >> 6, l = t & 63;
  int m = l & 15, q = l >> 4;
  int r0 = blockIdx.x * 128 + w * 16;          // tile0 base; tile1 = +64
  int arow0 = r0 + m;       if (arow0 > NN - 1) arow0 = NN - 1;
  int arow1 = r0 + 64 + m;  if (arow1 > NN - 1) arow1 = NN - 1;
  const unsigned short* hp0 = hb   + (size_t)arow0 * DF + q * 8;
  const unsigned short* ap0 = aggb + (size_t)arow0 * DF + q * 8;
  const unsigned short* hp1 = hb   + (size_t)arow1 * DF + q * 8;
  const unsigned short* ap1 = aggb + (size_t)arow1 * DF + q * 8;
  f32x4 acc0[8], acc1[8];
  for (int ct = 0; ct < 8; ++ct){
    float bbc = bias[ct * 16 + m];
    acc0[ct] = (f32x4){bbc, bbc, bbc, bbc};
    acc1[ct] = (f32x4){bbc, bbc, bbc, bbc};
  }
  for (int kt = 0; kt < 4; ++kt){
    bf16x8 a_h0 = *(const bf16x8*)(hp0 + kt * 32);
    bf16x8 a_g0 = *(const bf16x8*)(ap0 + kt * 32);
    bf16x8 a_h1 = *(const bf16x8*)(hp1 + kt * 32);
    bf16x8 a_g1 = *(const bf16x8*)(ap1 + kt * 32);
    int kg = kt * 4 + q;
    for (int ct = 0; ct < 8; ++ct){
      bf16x8 b_s = *(const bf16x8*)(WsB + (((kg << 7) + ct * 16 + m) << 3));
      bf16x8 b_n = *(const bf16x8*)(WnB + (((kg << 7) + ct * 16 + m) << 3));
      acc0[ct] = __builtin_amdgcn_mfma_f32_16x16x32_bf16(a_h0, b_s, acc0[ct], 0, 0, 0);
      acc0[ct] = __builtin_amdgcn_mfma_f32_16x16x32_bf16(a_g0, b_n, acc0[ct], 0, 0, 0);
      acc1[ct] = __builtin_amdgcn_mfma_f32_16x16x32_bf16(a_h1, b_s, acc1[ct], 0, 0, 0);
      acc1[ct] = __builtin_amdgcn_mfma_f32_16x16x32_bf16(a_g1, b_n, acc1[ct], 0, 0, 0);
    }
  }
  for (int ct = 0; ct < 8; ++ct){
    int col = ct * 16 + m;
    for (int reg = 0; reg < 4; ++reg){
      int row0 = r0 + q * 4 + reg;
      int row1 = row0 + 64;
      if (row0 < NN) hout[(size_t)row0 * DF + col] = f2bf(fmaxf(acc0[ct][reg], 0.f));
      if (row1 < NN) hout[(size_t)row1 * DF + col] = f2bf(fmaxf(acc1[ct][reg], 0.f));
    }
  }
}

// ---- pair GEMM via MFMA + fused BN column stats; src/tar via blockIdx.y ----
__global__ __launch_bounds__(256) void k_pair_mfma(
    const unsigned short* h2,
    const int* x1, const int* x2, const int* x1t, const int* x2t,
    const unsigned short* W1B, const float* b1, float* zbase, float* stats){
  __shared__ __align__(16) unsigned short F[64 * 392];
  __shared__ float csum[128], csq[128];
  int g = blockIdx.y;
  const int* ia = g ? x1t : x1;
  const int* ib = g ? x2t : x2;
  float* z = zbase + (size_t)g * NB * DF;
  int t = threadIdx.x;
  if (t < 128){ csum[t] = 0.f; csq[t] = 0.f; }
  int r0 = blockIdx.x * 64;
  int i = t >> 2, qq = t & 3;
  int r = r0 + i;
  int a = ia[r], b = ib[r];
  const unsigned short* pa = h2 + (size_t)a * DF + qq * 32;
  const unsigned short* pb = h2 + (size_t)b * DF + qq * 32;
  unsigned short* fr = F + i * 392;
  for (int jj = 0; jj < 4; ++jj){
    bf16x8 va = *(const bf16x8*)(pa + jj * 8);
    bf16x8 vb = *(const bf16x8*)(pb + jj * 8);
    *(bf16x8*)(fr + qq * 32 + jj * 8) = va;
    *(bf16x8*)(fr + 128 + qq * 32 + jj * 8) = vb;
    unsigned short d[8];
    for (int e = 0; e < 8; ++e){
      float fa = bf2f((unsigned short)va[e]);
      float fb = bf2f((unsigned short)vb[e]);
      d[e] = f2bf(fabsf(fa - fb));
    }
    *(bf16x8*)(fr + 256 + qq * 32 + jj * 8) = *(bf16x8*)d;
  }
  __syncthreads();
  int w = t >> 6, l = t & 63;
  int m = l & 15, q = l >> 4;
  int rl = w * 16 + m;
  f32x4 acc[8];
  for (int ct = 0; ct < 8; ++ct){
    float bbc = b1[ct * 16 + m];
    acc[ct] = (f32x4){bbc, bbc, bbc, bbc};
  }
  for (int kt = 0; kt < 12; ++kt){
    bf16x8 af = *(const bf16x8*)(F + rl * 392 + kt * 32 + q * 8);
    int kg = kt * 4 + q;
    for (int ct = 0; ct < 8; ++ct){
      bf16x8 bfr = *(const bf16x8*)(W1B + (((kg << 7) + ct * 16 + m) << 3));
      acc[ct] = __builtin_amdgcn_mfma_f32_16x16x32_bf16(af, bfr, acc[ct], 0, 0, 0);
    }
  }
  for (int ct = 0; ct < 8; ++ct){
    int col = ct * 16 + m;
    int row = r0 + w * 16 + q * 4;
    float s = 0.f, s2 = 0.f;
    for (int reg = 0; reg < 4; ++reg){
      float v = acc[ct][reg];
      z[(size_t)(row + reg) * DF + col] = v;
      s += v; s2 += v * v;
    }
    atomicAdd(&csum[col], s);
    atomicAdd(&csq[col], s2);
  }
  __syncthreads();
  if (t < 128){
    atomicAdd(&stats[g * 256 + t], csum[t]);
    atomicAdd(&stats[g * 256 + 128 + t], csq[t]);
  }
}

// ---- fused BN-normalize + relu + (src only) h_p GEMM, barrier-free ----
// One wave per 4 rows; 2 columns per lane; h_p dot via shfl_xor reduction.
__global__ __launch_bounds__(256) void k_norm_hp(
    const float* zbase, const float* stats,
    const float* gamma, const float* beta,
    const float* W2, const float* b2, float* mmd_base, float* hp){
  int g = blockIdx.y;
  int t = threadIdx.x;
  int w = t >> 6, l = t & 63;
  int c0 = l * 2, c1 = c0 + 1;
  float m0 = stats[g * 256 + c0] * (1.0f / NB);
  float m1 = stats[g * 256 + c1] * (1.0f / NB);
  float v0 = stats[g * 256 + 128 + c0] * (1.0f / NB) - m0 * m0;
  float v1 = stats[g * 256 + 128 + c1] * (1.0f / NB) - m1 * m1;
  float is0 = 1.0f / sqrtf(v0 + 1e-5f);
  float is1 = 1.0f / sqrtf(v1 + 1e-5f);
  float ga0 = gamma[c0], ga1 = gamma[c1];
  float be0 = beta[c0], be1 = beta[c1];
  float w200 = W2[c0 * 2], w201 = W2[c0 * 2 + 1];
  float w210 = W2[c1 * 2], w211 = W2[c1 * 2 + 1];
  const float* z = zbase + (size_t)g * NB * DF;
  float* mmd = mmd_base + (size_t)g * NB * DF;
  int rbase = blockIdx.x * 16 + w * 4;
  for (int rr = 0; rr < 4; ++rr){
    int row = rbase + rr;
    float2 zv = *(const float2*)(z + (size_t)row * DF + c0);
    float y0 = fmaxf((zv.x - m0) * is0 * ga0 + be0, 0.f);
    float y1 = fmaxf((zv.y - m1) * is1 * ga1 + be1, 0.f);
    float2 yv; yv.x = y0; yv.y = y1;
    *(float2*)(mmd + (size_t)row * DF + c0) = yv;
    if (g == 0){
      float s0 = y0 * w200 + y1 * w210;
      float s1 = y0 * w201 + y1 * w211;
      for (int o = 32; o > 0; o >>= 1){
        s0 += __shfl_xor(s0, o);
        s1 += __shfl_xor(s1, o);
      }
      if (l == 0){
        hp[row * 2]     = s0 + b2[0];
        hp[row * 2 + 1] = s1 + b2[1];
      }
    }
  }
}

extern "C" __attribute__((used, visibility("default")))
void kernel_launch(void* const* d_in, const int* in_sizes, int n_in,
                   void* d_out, int out_size, void* d_ws, size_t ws_size,
                   hipStream_t stream){
  const float* h_in  = (const float*)d_in[0];
  const int* esrc = (const int*)d_in[1];
  const int* edst = (const int*)d_in[2];
  const int* x1   = (const int*)d_in[3];
  const int* x2   = (const int*)d_in[4];
  const int* x1t  = (const int*)d_in[5];
  const int* x2t  = (const int*)d_in[6];
  const float* Wself = (const float*)d_in[7];
  const float* Wneigh= (const float*)d_in[8];
  const float* bconv = (const float*)d_in[9];
  const float* W1    = (const float*)d_in[10];
  const float* b1    = (const float*)d_in[11];
  const float* gamma = (const float*)d_in[12];
  const float* beta  = (const float*)d_in[13];
  const float* W2    = (const float*)d_in[14];
  const float* b2    = (const float*)d_in[15];
  float* out = (float*)d_out;                   // fp32 outputs
  float* hp_out   = out;                        // [NB,2]
  float* mmd_base = out + 2 * NB;               // [2][NB,DF] contiguous

  // ---- workspace layout (~45.8 MB) ----
  float* zreg  = (float*)d_ws;                       // 2*NB*DF f32 (src|tar)
  unsigned short* aggb = (unsigned short*)zreg;      // alias (dead before z)
  float* stats = zreg + (size_t)2 * NB * DF;         // 512
  float* mstd  = stats + 512;                        // 512 (layout pad)
  float* dinv  = mstd + 512;                         // 50,048 (unused slot)
  int* cnt  = (int*)(dinv + 50048);                  // 50,000
  int* fill = cnt + NN;                              // 50,000
  int* rp   = fill + NN;                             // 50,016
  int* perm = rp + 50016;                            // 600,000
  int* bsum = perm + 600000;                         // 256
  unsigned short* h_c = (unsigned short*)(bsum + 256);    // NN*DF u16
  unsigned short* h1b = h_c + (size_t)NN * DF;            // NN*DF u16
  unsigned short* h2b = h_c;                 // alias: h_c dead after layer 0
  unsigned short* WsB = h1b + (size_t)NN * DF;  // 2*DF*DF u16 (both layers)
  unsigned short* WnB = WsB + 2 * DF * DF;      // 2*DF*DF u16
  unsigned short* W1B = WnB + 2 * DF * DF;      // 3*DF*DF u16
  (void)dinv;

  // fused prelude: h cast + zeroing + weight swizzle
  k_prelude<<<3710, 256, 0, stream>>>(h_in, h_c, Wself, Wneigh, W1,
                                      WsB, WnB, W1B, cnt, stats);

  // CSR build (scan2 folded into scan3)
  k_hist<<<(NE + 255) / 256, 256, 0, stream>>>(edst, cnt);
  k_scan1<<<196, 256, 0, stream>>>(cnt, bsum);
  k_scan3<<<196, 256, 0, stream>>>(cnt, bsum, rp);
  k_scatter<<<(NE + 255) / 256, 256, 0, stream>>>(esrc, edst, rp, fill, perm);

  // SAGE layer 0: h_c -> h1b
  k_agg<<<(NN + 3) / 4, 256, 0, stream>>>((const unsigned int*)h_c, rp, perm,
                                          (unsigned int*)aggb);
  k_layer_mfma<<<(NN + 127) / 128, 256, 0, stream>>>(h_c, aggb, WsB, WnB,
                                                     bconv, h1b);
  // SAGE layer 1: h1b -> h2b
  k_agg<<<(NN + 3) / 4, 256, 0, stream>>>((const unsigned int*)h1b, rp, perm,
                                          (unsigned int*)aggb);
  k_layer_mfma<<<(NN + 127) / 128, 256, 0, stream>>>(h1b, aggb, WsB + DF * DF,
                                                     WnB + DF * DF, bconv + DF,
                                                     h2b);

  // head: pair GEMM (+ fused col-stats), then normalize (+ fused h_p)
  k_pair_mfma<<<dim3(NB / 64, 2), 256, 0, stream>>>(h2b, x1, x2, x1t, x2t,
                                                    W1B, b1, zreg, stats);
  k_norm_hp<<<dim3(NB / 16, 2), 256, 0, stream>>>(zreg, stats, gamma, beta,
                                                  W2, b2, mmd_base, hp_out);
}